// Round 1
// baseline (211.358 us; speedup 1.0000x reference)
//
#include <hip/hip_runtime.h>

// ---------------------------------------------------------------------------
// Fused MHRPR chunk-attention layer for MI355X (gfx950).
// One block = one chunk (64 tokens). 8 waves = 8 heads.
// Pipeline per block: QKV projections (bf16 MFMA, K=512) -> per-head 64x64
// attention with relative-position bias -> output projection -> out*(mask).
// Only global scratch: bf16 copies of Wq,Wk,Wv,Wo (2 MB in d_ws).
// ---------------------------------------------------------------------------

typedef __attribute__((ext_vector_type(8))) short short8;   // 8 bf16 (4 VGPRs)
typedef __attribute__((ext_vector_type(4))) float f32x4;    // MFMA accum
typedef __attribute__((ext_vector_type(2))) unsigned int uint2v;
typedef __attribute__((ext_vector_type(4))) unsigned short ushort4v;

#define DEV static __device__ __forceinline__

DEV unsigned short f2bf(float f) {                 // f32 -> bf16 RNE
  union { float f; unsigned int u; } x; x.f = f;
  unsigned int r = x.u + 0x7fffu + ((x.u >> 16) & 1u);
  return (unsigned short)(r >> 16);
}
DEV float bf2f(unsigned short h) {
  union { unsigned int u; float f; } x; x.u = ((unsigned int)h) << 16;
  return x.f;
}

constexpr int Bn = 4, Dm = 512, Tn = 8192, NC = 64;
constexpr int Gn = Tn / NC;     // 128 chunks per batch
constexpr int BG = Bn * Gn;     // 512 blocks
constexpr int WSZ = Dm * Dm;    // 262144 elems per weight matrix

// --- weights f32 -> bf16 (Wq | Wk | Wv | Wo contiguous in ws) ---------------
__global__ void wcvt_kernel(const float* __restrict__ wq, const float* __restrict__ wk,
                            const float* __restrict__ wv, const float* __restrict__ wo,
                            unsigned short* __restrict__ dst) {
  int i = (blockIdx.x * blockDim.x + threadIdx.x) * 4;   // 1024*256*4 == 4*WSZ
  const float* src = (i < WSZ) ? wq : (i < 2 * WSZ) ? wk : (i < 3 * WSZ) ? wv : wo;
  int off = i & (WSZ - 1);
  f32x4 v = *(const f32x4*)(src + off);
  ushort4v o;
  o[0] = f2bf(v[0]); o[1] = f2bf(v[1]); o[2] = f2bf(v[2]); o[3] = f2bf(v[3]);
  *(ushort4v*)(dst + i) = o;
}

// ---------------------------------------------------------------------------
__global__ __launch_bounds__(512, 2)
void fused_kernel(const float* __restrict__ qx, const float* __restrict__ kx,
                  const float* __restrict__ vx, const float* __restrict__ masks,
                  const unsigned short* __restrict__ wbf,
                  const float* __restrict__ bq, const float* __restrict__ bk,
                  const float* __restrict__ bv, const float* __restrict__ bo,
                  const float* __restrict__ relk, const float* __restrict__ relv,
                  float* __restrict__ out)
{
  extern __shared__ char lds[];
  const int tid  = threadIdx.x;
  const int lane = tid & 63;
  const int w    = tid >> 6;        // wave id == head id
  const int l15  = lane & 15;
  const int lg   = lane >> 4;
  const int c    = blockIdx.x;      // chunk id
  const int b    = c >> 7;
  const int t0   = (c & (Gn - 1)) * NC;

  // LDS map: [0,16K) x-staging | per-wave 16K regions: regA(8K)+regB(8K)
  char* xbuf = lds;
  char* regA = lds + 16 * 1024 + w * 16 * 1024;  // Q tile, later V tile
  char* regB = regA + 8 * 1024;                  // K tile, later P tile

  // --- key padding mask (ref: all-zero chunks are unmasked) ---
  float cmv = masks[(size_t)b * Tn + t0 + lane];
  unsigned long long nzb = __ballot(cmv != 0.0f);
  unsigned long long kpm = (nzb == 0ull) ? 0ull : __ballot(cmv == 0.0f);

  const f32x4 fzero = {0.f, 0.f, 0.f, 0.f};

  // --- projection: acc[mi][ni][rr] = P^T[t = mi*16+lg*4+rr][o = 64w+ni*16+l15]
  auto project = [&](const float* __restrict__ xin, const unsigned short* __restrict__ Wp,
                     f32x4 (&acc)[4][4]) {
#pragma unroll
    for (int mi = 0; mi < 4; ++mi)
#pragma unroll
      for (int ni = 0; ni < 4; ++ni) acc[mi][ni] = fzero;
    const size_t xbase = (size_t)b * Dm * Tn + t0 + lane;
    for (int s = 0; s < 4; ++s) {                 // K slices of 128
      const int d0 = s * 128;
      short8 xs[2];
#pragma unroll
      for (int cc = 0; cc < 2; ++cc)
#pragma unroll
        for (int j = 0; j < 8; ++j) {
          float f = xin[xbase + (size_t)(d0 + 16 * w + 8 * cc + j) * Tn];
          xs[cc][j] = (short)f2bf(f);
        }
      short8 wf[4][4];                            // W^T frags (B operand)
#pragma unroll
      for (int ni = 0; ni < 4; ++ni)
#pragma unroll
        for (int kk = 0; kk < 4; ++kk) {
          int o = 64 * w + ni * 16 + l15;
          int d = d0 + kk * 32 + lg * 8;
          wf[ni][kk] = *(const short8*)(Wp + o * Dm + d);
        }
      __syncthreads();                            // prev slice consumed
#pragma unroll
      for (int cc = 0; cc < 2; ++cc) {            // Sx[t=lane][d'] swz ^((t&15)<<4)
        int off = (lane * 256 + (16 * w + 8 * cc) * 2) ^ ((lane & 15) << 4);
        *(short8*)(xbuf + off) = xs[cc];
      }
      __syncthreads();
#pragma unroll
      for (int kk = 0; kk < 4; ++kk) {
        short8 af[4];
#pragma unroll
        for (int mi = 0; mi < 4; ++mi) {
          int t = mi * 16 + l15;
          int off = (t * 256 + (kk * 32 + lg * 8) * 2) ^ ((t & 15) << 4);
          af[mi] = *(const short8*)(xbuf + off);
        }
#pragma unroll
        for (int ni = 0; ni < 4; ++ni)
#pragma unroll
          for (int mi = 0; mi < 4; ++mi)
            acc[mi][ni] = __builtin_amdgcn_mfma_f32_16x16x32_bf16(af[mi], wf[ni][kk],
                                                                  acc[mi][ni], 0, 0, 0);
      }
    }
  };

  f32x4 acc[4][4];

  // ---- Q projection -> regA as St_Q[t][hd] (128B rows, swz ^((t&7)<<4)) ----
  project(qx, wbf + 0 * WSZ, acc);
#pragma unroll
  for (int ni = 0; ni < 4; ++ni) {
    float bia = bq[64 * w + ni * 16 + l15];
    int hd = ni * 16 + l15;
#pragma unroll
    for (int mi = 0; mi < 4; ++mi)
#pragma unroll
      for (int rr = 0; rr < 4; ++rr) {
        int t = mi * 16 + lg * 4 + rr;
        int off = (t * 128 + hd * 2) ^ ((t & 7) << 4);
        *(unsigned short*)(regA + off) = f2bf(acc[mi][ni][rr] + bia);
      }
  }

  // ---- K projection -> regB as St_K[t][hd] ----
  project(kx, wbf + 1 * WSZ, acc);
#pragma unroll
  for (int ni = 0; ni < 4; ++ni) {
    float bia = bk[64 * w + ni * 16 + l15];
    int hd = ni * 16 + l15;
#pragma unroll
    for (int mi = 0; mi < 4; ++mi)
#pragma unroll
      for (int rr = 0; rr < 4; ++rr) {
        int t = mi * 16 + lg * 4 + rr;
        int off = (t * 128 + hd * 2) ^ ((t & 7) << 4);
        *(unsigned short*)(regB + off) = f2bf(acc[mi][ni][rr] + bia);
      }
  }

  // ---- S = Q^T K (M=qt, N=kt, K=hd=64) ----
  f32x4 sacc[4][4];
#pragma unroll
  for (int mi = 0; mi < 4; ++mi)
#pragma unroll
    for (int ni = 0; ni < 4; ++ni) sacc[mi][ni] = fzero;
#pragma unroll
  for (int kk = 0; kk < 2; ++kk) {
    short8 aq[4], bkf[4];
#pragma unroll
    for (int mi = 0; mi < 4; ++mi) {
      int t = mi * 16 + l15;
      int off = (t * 128 + (kk * 32 + lg * 8) * 2) ^ ((t & 7) << 4);
      aq[mi]  = *(const short8*)(regA + off);
      bkf[mi] = *(const short8*)(regB + off);
    }
#pragma unroll
    for (int ni = 0; ni < 4; ++ni)
#pragma unroll
      for (int mi = 0; mi < 4; ++mi)
        sacc[mi][ni] = __builtin_amdgcn_mfma_f32_16x16x32_bf16(aq[mi], bkf[ni],
                                                               sacc[mi][ni], 0, 0, 0);
  }

  // ---- qrel[r] = sum_hd Q[hd][qt=lane] * rel_k[r][hd]  (5 dots per row) ----
  float qr0 = 0, qr1 = 0, qr2 = 0, qr3 = 0, qr4 = 0;
#pragma unroll
  for (int g = 0; g < 8; ++g) {
    short8 q8 = *(const short8*)(regA + ((lane * 128 + g * 16) ^ ((lane & 7) << 4)));
#pragma unroll
    for (int j = 0; j < 8; ++j) {
      float qf = bf2f((unsigned short)q8[j]);
      qr0 += qf * relk[0 * 64 + g * 8 + j];
      qr1 += qf * relk[1 * 64 + g * 8 + j];
      qr2 += qf * relk[2 * 64 + g * 8 + j];
      qr3 += qf * relk[3 * 64 + g * 8 + j];
      qr4 += qf * relk[4 * 64 + g * 8 + j];
    }
  }

  // ---- S epilogue: +attn2, /8, mask, softmax; P -> regB [qt][kt] ----
  const float scale = 0.125f;
#pragma unroll
  for (int mi = 0; mi < 4; ++mi)
#pragma unroll
    for (int rr = 0; rr < 4; ++rr) {
      int qt = mi * 16 + lg * 4 + rr;
      float q0 = __shfl(qr0, qt), q1 = __shfl(qr1, qt), q2 = __shfl(qr2, qt),
            q3 = __shfl(qr3, qt), q4 = __shfl(qr4, qt);
      float sv[4];
#pragma unroll
      for (int ni = 0; ni < 4; ++ni) {
        int kt = ni * 16 + l15;
        int dd = kt - qt;
        float a2 = (dd <= -2) ? q0 : (dd == -1) ? q1 : (dd == 0) ? q2 : (dd == 1) ? q3 : q4;
        float s = (sacc[mi][ni][rr] + a2) * scale;
        if ((kpm >> kt) & 1ull) s = -1e30f;
        sv[ni] = s;
      }
      float m = fmaxf(fmaxf(sv[0], sv[1]), fmaxf(sv[2], sv[3]));
#pragma unroll
      for (int xm = 1; xm < 16; xm <<= 1) m = fmaxf(m, __shfl_xor(m, xm));
      float ssum = 0.f;
#pragma unroll
      for (int ni = 0; ni < 4; ++ni) { sv[ni] = __expf(sv[ni] - m); ssum += sv[ni]; }
#pragma unroll
      for (int xm = 1; xm < 16; xm <<= 1) ssum += __shfl_xor(ssum, xm);
      float inv = 1.0f / ssum;
#pragma unroll
      for (int ni = 0; ni < 4; ++ni) {
        int kt = ni * 16 + l15;
        int off = (qt * 128 + kt * 2) ^ ((qt & 7) << 4);
        *(unsigned short*)(regB + off) = f2bf(sv[ni] * inv);
      }
    }

  // ---- psum[qt=lane][r]: 5 class sums of P row (prefix/point structure) ----
  float ps0 = 0, ps1 = 0, ps2 = 0, ps3 = 0, tot = 0;
#pragma unroll
  for (int g = 0; g < 8; ++g) {
    short8 p8 = *(const short8*)(regB + ((lane * 128 + g * 16) ^ ((lane & 7) << 4)));
#pragma unroll
    for (int j = 0; j < 8; ++j) {
      int kt = g * 8 + j;
      float p = bf2f((unsigned short)p8[j]);
      int dd = kt - lane;
      tot += p;
      ps0 += (dd <= -2) ? p : 0.f;
      ps1  = (dd == -1) ? p : ps1;
      ps2  = (dd ==  0) ? p : ps2;
      ps3  = (dd ==  1) ? p : ps3;
    }
  }
  float ps4 = tot - ps0 - ps1 - ps2 - ps3;

  // ---- V projection -> regA as St_V[hd][t] (transposed store, b64 packs) ----
  project(vx, wbf + 2 * WSZ, acc);
#pragma unroll
  for (int ni = 0; ni < 4; ++ni) {
    float bia = bv[64 * w + ni * 16 + l15];
    int hd = ni * 16 + l15;
#pragma unroll
    for (int mi = 0; mi < 4; ++mi) {
      unsigned int lo = (unsigned int)f2bf(acc[mi][ni][0] + bia) |
                        ((unsigned int)f2bf(acc[mi][ni][1] + bia) << 16);
      unsigned int hi = (unsigned int)f2bf(acc[mi][ni][2] + bia) |
                        ((unsigned int)f2bf(acc[mi][ni][3] + bia) << 16);
      uint2v pk; pk[0] = lo; pk[1] = hi;
      int off = (hd * 128 + (mi * 16 + lg * 4) * 2) ^ ((hd & 7) << 4);
      *(uint2v*)(regA + off) = pk;
    }
  }

  // ---- O^T = V * P^T (M=hd, N=qt, K=kt) ----
  f32x4 oacc[4][4];
#pragma unroll
  for (int mi = 0; mi < 4; ++mi)
#pragma unroll
    for (int ni = 0; ni < 4; ++ni) oacc[mi][ni] = fzero;
#pragma unroll
  for (int kk = 0; kk < 2; ++kk) {
    short8 av[4], bp[4];
#pragma unroll
    for (int mi = 0; mi < 4; ++mi) {
      int row = mi * 16 + l15;   // hd for A (V), qt for B (P)
      int off = (row * 128 + (kk * 32 + lg * 8) * 2) ^ ((row & 7) << 4);
      av[mi] = *(const short8*)(regA + off);
      bp[mi] = *(const short8*)(regB + off);
    }
#pragma unroll
    for (int ni = 0; ni < 4; ++ni)
#pragma unroll
      for (int mi = 0; mi < 4; ++mi)
        oacc[mi][ni] = __builtin_amdgcn_mfma_f32_16x16x32_bf16(av[mi], bp[ni],
                                                               oacc[mi][ni], 0, 0, 0);
  }

  // ---- O epilogue: +w2 (psum x rel_v), pack xo bf16 ----
  float psh0[4], psh1[4], psh2[4], psh3[4], psh4[4];
#pragma unroll
  for (int ni = 0; ni < 4; ++ni) {
    int qt2 = ni * 16 + l15;
    psh0[ni] = __shfl(ps0, qt2); psh1[ni] = __shfl(ps1, qt2); psh2[ni] = __shfl(ps2, qt2);
    psh3[ni] = __shfl(ps3, qt2); psh4[ni] = __shfl(ps4, qt2);
  }
  uint2v xop[4][4];
#pragma unroll
  for (int mi = 0; mi < 4; ++mi) {
    float rv_[4][5];
#pragma unroll
    for (int rr = 0; rr < 4; ++rr) {
      int hd = mi * 16 + lg * 4 + rr;
#pragma unroll
      for (int r = 0; r < 5; ++r) rv_[rr][r] = relv[r * 64 + hd];
    }
#pragma unroll
    for (int ni = 0; ni < 4; ++ni) {
      unsigned short u[4];
#pragma unroll
      for (int rr = 0; rr < 4; ++rr) {
        float w2 = psh0[ni] * rv_[rr][0] + psh1[ni] * rv_[rr][1] + psh2[ni] * rv_[rr][2]
                 + psh3[ni] * rv_[rr][3] + psh4[ni] * rv_[rr][4];
        u[rr] = f2bf(oacc[mi][ni][rr] + w2);
      }
      uint2v pk; pk[0] = u[0] | ((unsigned int)u[1] << 16);
      pk[1] = u[2] | ((unsigned int)u[3] << 16);
      xop[mi][ni] = pk;
    }
  }

  // ---- xo -> shared [t][d] (1KB rows, swz ^((t&15)<<4)); reuses wave regions
  __syncthreads();
  char* xobuf = lds + 16 * 1024;   // 64 KB
#pragma unroll
  for (int ni = 0; ni < 4; ++ni) {
    int t = ni * 16 + l15;
#pragma unroll
    for (int mi = 0; mi < 4; ++mi) {
      int d = 64 * w + mi * 16 + lg * 4;
      int off = (t * 1024 + d * 2) ^ ((t & 15) << 4);
      *(uint2v*)(xobuf + off) = xop[mi][ni];
    }
  }
  __syncthreads();

  // ---- out = Wo * xo + bo, *mask; wave w covers o in [64w, 64w+64) ----
  f32x4 cacc[4][4];
#pragma unroll
  for (int mi = 0; mi < 4; ++mi)
#pragma unroll
    for (int ni = 0; ni < 4; ++ni) cacc[mi][ni] = fzero;
  const unsigned short* Wo = wbf + 3 * WSZ;
#pragma unroll
  for (int kk = 0; kk < 16; ++kk) {
    short8 ax[4], bw[4];
#pragma unroll
    for (int mi = 0; mi < 4; ++mi) {
      int t = mi * 16 + l15;
      int off = (t * 1024 + (kk * 32 + lg * 8) * 2) ^ ((t & 15) << 4);
      ax[mi] = *(const short8*)(xobuf + off);
    }
#pragma unroll
    for (int ni = 0; ni < 4; ++ni) {
      int o = 64 * w + ni * 16 + l15;
      bw[ni] = *(const short8*)(Wo + o * Dm + kk * 32 + lg * 8);
    }
#pragma unroll
    for (int ni = 0; ni < 4; ++ni)
#pragma unroll
      for (int mi = 0; mi < 4; ++mi)
        cacc[mi][ni] = __builtin_amdgcn_mfma_f32_16x16x32_bf16(ax[mi], bw[ni],
                                                               cacc[mi][ni], 0, 0, 0);
  }
#pragma unroll
  for (int mi = 0; mi < 4; ++mi) {
    int tl = mi * 16 + lg * 4;
    f32x4 mv = *(const f32x4*)(masks + (size_t)b * Tn + t0 + tl);
#pragma unroll
    for (int ni = 0; ni < 4; ++ni) {
      int o = 64 * w + ni * 16 + l15;
      float bia = bo[o];
      f32x4 r;
#pragma unroll
      for (int rr = 0; rr < 4; ++rr) r[rr] = (cacc[mi][ni][rr] + bia) * mv[rr];
      *(f32x4*)(out + ((size_t)b * Dm + o) * Tn + t0 + tl) = r;
    }
  }
}

// ---------------------------------------------------------------------------
extern "C" void kernel_launch(void* const* d_in, const int* in_sizes, int n_in,
                              void* d_out, int out_size, void* d_ws, size_t ws_size,
                              hipStream_t stream) {
  (void)in_sizes; (void)n_in; (void)out_size; (void)ws_size;
  const float* q  = (const float*)d_in[0];
  const float* k  = (const float*)d_in[1];
  const float* v  = (const float*)d_in[2];
  const float* ms = (const float*)d_in[3];
  const float* Wq = (const float*)d_in[4];
  const float* bq = (const float*)d_in[5];
  const float* Wk = (const float*)d_in[6];
  const float* bk = (const float*)d_in[7];
  const float* Wv = (const float*)d_in[8];
  const float* bv = (const float*)d_in[9];
  const float* Wo = (const float*)d_in[10];
  const float* bo = (const float*)d_in[11];
  const float* rk = (const float*)d_in[12];
  const float* rv = (const float*)d_in[13];
  unsigned short* wbf = (unsigned short*)d_ws;   // 2 MB bf16 weights
  float* out = (float*)d_out;

  wcvt_kernel<<<dim3(1024), dim3(256), 0, stream>>>(Wq, Wk, Wv, Wo, wbf);

  hipFuncSetAttribute((const void*)fused_kernel,
                      hipFuncAttributeMaxDynamicSharedMemorySize, 147456);
  fused_kernel<<<dim3(BG), dim3(512), 147456, stream>>>(q, k, v, ms, wbf,
                                                        bq, bk, bv, bo, rk, rv, out);
}

// Round 2
// 210.646 us; speedup vs baseline: 1.0034x; 1.0034x over previous
//
#include <hip/hip_runtime.h>

// ---------------------------------------------------------------------------
// MHRPR chunk-attention, split pipeline for MI355X (gfx950):
//   wcvt_tiled : weights f32 -> bf16, MFMA-fragment tiling
//   xpose      : x q/k/v (B,D,T) f32 -> per-chunk tiled bf16 (B*g, 64, 512)
//   fused2     : per-chunk fused QKV proj + rel-pos attention + out proj,
//                projections read operands straight from global (L2),
//                only 2 block barriers.
// Fallback to the round-1 monolithic kernel if ws_size is too small.
// ---------------------------------------------------------------------------

typedef __attribute__((ext_vector_type(8))) short short8;   // 8 bf16
typedef __attribute__((ext_vector_type(4))) float f32x4;
typedef __attribute__((ext_vector_type(2))) unsigned int uint2v;
typedef __attribute__((ext_vector_type(4))) unsigned short ushort4v;

#define DEV static __device__ __forceinline__

DEV unsigned short f2bf(float f) {                 // f32 -> bf16 RNE
  union { float f; unsigned int u; } x; x.f = f;
  unsigned int r = x.u + 0x7fffu + ((x.u >> 16) & 1u);
  return (unsigned short)(r >> 16);
}
DEV float bf2f(unsigned short h) {
  union { unsigned int u; float f; } x; x.u = ((unsigned int)h) << 16;
  return x.f;
}

constexpr int Bn = 4, Dm = 512, Tn = 8192, NC = 64;
constexpr int Gn = Tn / NC;            // 128
constexpr int BG = Bn * Gn;            // 512 chunks
constexpr int WSZ = Dm * Dm;           // 262144
constexpr size_t XTSZ = (size_t)Bn * Tn * Dm;   // 16777216 elems per tensor

// ---------------------------------------------------------------------------
// Weights -> bf16 tiled: off = m*WSZ + (o>>6)*32768 + (d>>5)*2048 + (o&63)*32 + (d&31)
__global__ __launch_bounds__(256) void wcvt_tiled(
    const float* __restrict__ wq, const float* __restrict__ wk,
    const float* __restrict__ wv, const float* __restrict__ wo,
    unsigned short* __restrict__ dst) {
  int i = blockIdx.x * 256 + threadIdx.x;          // 262144 float4 total
  int m = i >> 16, fi = i & 65535;
  int o = fi >> 7, d = (fi & 127) << 2;
  const float* src = (m == 0) ? wq : (m == 1) ? wk : (m == 2) ? wv : wo;
  f32x4 v = *(const f32x4*)(src + o * Dm + d);
  ushort4v u;
  u[0] = f2bf(v[0]); u[1] = f2bf(v[1]); u[2] = f2bf(v[2]); u[3] = f2bf(v[3]);
  int doff = m * WSZ + ((o >> 6) << 15) + ((d >> 5) << 11) + ((o & 63) << 5) + (d & 31);
  *(ushort4v*)(dst + doff) = u;
}

// ---------------------------------------------------------------------------
// x (B,D,T) f32 -> tiled bf16: per (tensor,chunk): off = c*32768 + (d>>5)*2048 + t*32 + (d&31)
__global__ __launch_bounds__(256) void xpose_kernel(
    const float* __restrict__ q, const float* __restrict__ k,
    const float* __restrict__ v, unsigned short* __restrict__ xt) {
  __shared__ unsigned short tile[64 * 65];
  const int tid = threadIdx.x, bid = blockIdx.x;
  const int tz = bid >> 12, rem = bid & 4095;
  const int cid = rem >> 3, dh = rem & 7;          // chunk 0..511, d-half 0..7
  const int b = cid >> 7, t0 = (cid & 127) * 64, d0 = dh * 64;
  const float* xin = (tz == 0) ? q : (tz == 1) ? k : v;
  const int lane = tid & 63, drow = tid >> 6;
  const size_t base = (size_t)b * Dm * Tn + t0 + lane;
#pragma unroll
  for (int p = 0; p < 16; ++p) {
    int dr = drow + p * 4;
    float f = xin[base + (size_t)(d0 + dr) * Tn];
    tile[lane * 65 + dr] = f2bf(f);
  }
  __syncthreads();
  unsigned short* xb = xt + (size_t)tz * XTSZ + ((size_t)cid << 15) + (dh << 12);
  const int t = tid >> 2, dlo = (tid & 3) * 8;
#pragma unroll
  for (int h = 0; h < 2; ++h) {
    short8 s;
#pragma unroll
    for (int j = 0; j < 8; ++j) s[j] = (short)tile[t * 65 + h * 32 + dlo + j];
    *(short8*)(xb + h * 2048 + t * 32 + dlo) = s;
  }
}

// ---------------------------------------------------------------------------
__global__ __launch_bounds__(512, 2)
void fused2_kernel(const unsigned short* __restrict__ xt,
                   const float* __restrict__ masks,
                   const unsigned short* __restrict__ wbf,
                   const float* __restrict__ bq, const float* __restrict__ bk,
                   const float* __restrict__ bv, const float* __restrict__ bo,
                   const float* __restrict__ relk, const float* __restrict__ relv,
                   float* __restrict__ out)
{
  extern __shared__ char lds[];
  const int tid  = threadIdx.x;
  const int lane = tid & 63;
  const int w    = tid >> 6;        // wave id == head id
  const int l15  = lane & 15;
  const int lg   = lane >> 4;
  const int c    = blockIdx.x;
  const int b    = c >> 7;
  const int t0   = (c & (Gn - 1)) * NC;

  char* regA = lds + w * 16384;     // Q tile, later V tile (8KB)
  char* regB = regA + 8192;         // K tile, later P tile (8KB)

  float cmv = masks[(size_t)b * Tn + t0 + lane];
  unsigned long long nzb = __ballot(cmv != 0.0f);
  unsigned long long kpm = (nzb == 0ull) ? 0ull : __ballot(cmv == 0.0f);

  const f32x4 fzero = {0.f, 0.f, 0.f, 0.f};
  const int aoff = l15 * 32 + lg * 8;                  // fragment lane offset
  const unsigned short* xq = xt + ((size_t)c << 15);
  const unsigned short* xk = xq + XTSZ;
  const unsigned short* xv = xq + 2 * XTSZ;

  // projection: both operands straight from global (tiled), no LDS, no barrier
  auto project = [&](const unsigned short* __restrict__ xb,
                     const unsigned short* __restrict__ wb, f32x4 (&acc)[4][4]) {
#pragma unroll
    for (int mi = 0; mi < 4; ++mi)
#pragma unroll
      for (int ni = 0; ni < 4; ++ni) acc[mi][ni] = fzero;
#pragma unroll
    for (int kk = 0; kk < 16; ++kk) {
      short8 af[4], bf_[4];
#pragma unroll
      for (int mi = 0; mi < 4; ++mi)
        af[mi] = *(const short8*)(xb + kk * 2048 + mi * 512 + aoff);
#pragma unroll
      for (int ni = 0; ni < 4; ++ni)
        bf_[ni] = *(const short8*)(wb + kk * 2048 + ni * 512 + aoff);
#pragma unroll
      for (int ni = 0; ni < 4; ++ni)
#pragma unroll
        for (int mi = 0; mi < 4; ++mi)
          acc[mi][ni] = __builtin_amdgcn_mfma_f32_16x16x32_bf16(af[mi], bf_[ni],
                                                                acc[mi][ni], 0, 0, 0);
    }
  };

  f32x4 acc[4][4];

  // ---- Q projection -> regA as St_Q[t][hd] (128B rows, swz ^((t&7)<<4)) ----
  project(xq, wbf + 0 * WSZ + w * 32768, acc);
#pragma unroll
  for (int ni = 0; ni < 4; ++ni) {
    float bia = bq[64 * w + ni * 16 + l15];
    int hd = ni * 16 + l15;
#pragma unroll
    for (int mi = 0; mi < 4; ++mi)
#pragma unroll
      for (int rr = 0; rr < 4; ++rr) {
        int t = mi * 16 + lg * 4 + rr;
        int off = (t * 128 + hd * 2) ^ ((t & 7) << 4);
        *(unsigned short*)(regA + off) = f2bf(acc[mi][ni][rr] + bia);
      }
  }

  // ---- K projection -> regB as St_K[t][hd] ----
  project(xk, wbf + 1 * WSZ + w * 32768, acc);
#pragma unroll
  for (int ni = 0; ni < 4; ++ni) {
    float bia = bk[64 * w + ni * 16 + l15];
    int hd = ni * 16 + l15;
#pragma unroll
    for (int mi = 0; mi < 4; ++mi)
#pragma unroll
      for (int rr = 0; rr < 4; ++rr) {
        int t = mi * 16 + lg * 4 + rr;
        int off = (t * 128 + hd * 2) ^ ((t & 7) << 4);
        *(unsigned short*)(regB + off) = f2bf(acc[mi][ni][rr] + bia);
      }
  }

  // ---- S = Q K^T (M=qt, N=kt, K=hd=64) ----
  f32x4 sacc[4][4];
#pragma unroll
  for (int mi = 0; mi < 4; ++mi)
#pragma unroll
    for (int ni = 0; ni < 4; ++ni) sacc[mi][ni] = fzero;
#pragma unroll
  for (int kk = 0; kk < 2; ++kk) {
    short8 aq[4], bkf[4];
#pragma unroll
    for (int mi = 0; mi < 4; ++mi) {
      int t = mi * 16 + l15;
      int off = (t * 128 + (kk * 32 + lg * 8) * 2) ^ ((t & 7) << 4);
      aq[mi]  = *(const short8*)(regA + off);
      bkf[mi] = *(const short8*)(regB + off);
    }
#pragma unroll
    for (int ni = 0; ni < 4; ++ni)
#pragma unroll
      for (int mi = 0; mi < 4; ++mi)
        sacc[mi][ni] = __builtin_amdgcn_mfma_f32_16x16x32_bf16(aq[mi], bkf[ni],
                                                               sacc[mi][ni], 0, 0, 0);
  }

  // ---- qrel[r] = sum_hd Q[qt=lane][hd] * rel_k[r][hd] ----
  float qr0 = 0, qr1 = 0, qr2 = 0, qr3 = 0, qr4 = 0;
#pragma unroll
  for (int g = 0; g < 8; ++g) {
    short8 q8 = *(const short8*)(regA + ((lane * 128 + g * 16) ^ ((lane & 7) << 4)));
#pragma unroll
    for (int j = 0; j < 8; ++j) {
      float qf = bf2f((unsigned short)q8[j]);
      qr0 += qf * relk[0 * 64 + g * 8 + j];
      qr1 += qf * relk[1 * 64 + g * 8 + j];
      qr2 += qf * relk[2 * 64 + g * 8 + j];
      qr3 += qf * relk[3 * 64 + g * 8 + j];
      qr4 += qf * relk[4 * 64 + g * 8 + j];
    }
  }

  // ---- S epilogue: +attn2, /8, mask, softmax; P -> regB [qt][kt] ----
  const float scale = 0.125f;
#pragma unroll
  for (int mi = 0; mi < 4; ++mi)
#pragma unroll
    for (int rr = 0; rr < 4; ++rr) {
      int qt = mi * 16 + lg * 4 + rr;
      float q0 = __shfl(qr0, qt), q1 = __shfl(qr1, qt), q2 = __shfl(qr2, qt),
            q3 = __shfl(qr3, qt), q4 = __shfl(qr4, qt);
      float sv[4];
#pragma unroll
      for (int ni = 0; ni < 4; ++ni) {
        int kt = ni * 16 + l15;
        int dd = kt - qt;
        float a2 = (dd <= -2) ? q0 : (dd == -1) ? q1 : (dd == 0) ? q2 : (dd == 1) ? q3 : q4;
        float s = (sacc[mi][ni][rr] + a2) * scale;
        if ((kpm >> kt) & 1ull) s = -1e30f;
        sv[ni] = s;
      }
      float m = fmaxf(fmaxf(sv[0], sv[1]), fmaxf(sv[2], sv[3]));
#pragma unroll
      for (int xm = 1; xm < 16; xm <<= 1) m = fmaxf(m, __shfl_xor(m, xm));
      float ssum = 0.f;
#pragma unroll
      for (int ni = 0; ni < 4; ++ni) { sv[ni] = __expf(sv[ni] - m); ssum += sv[ni]; }
#pragma unroll
      for (int xm = 1; xm < 16; xm <<= 1) ssum += __shfl_xor(ssum, xm);
      float inv = 1.0f / ssum;
#pragma unroll
      for (int ni = 0; ni < 4; ++ni) {
        int kt = ni * 16 + l15;
        int off = (qt * 128 + kt * 2) ^ ((qt & 7) << 4);
        *(unsigned short*)(regB + off) = f2bf(sv[ni] * inv);
      }
    }

  // ---- psum[qt=lane][r]: 5 class sums of P row ----
  float ps0 = 0, ps1 = 0, ps2 = 0, ps3 = 0, tot = 0;
#pragma unroll
  for (int g = 0; g < 8; ++g) {
    short8 p8 = *(const short8*)(regB + ((lane * 128 + g * 16) ^ ((lane & 7) << 4)));
#pragma unroll
    for (int j = 0; j < 8; ++j) {
      int kt = g * 8 + j;
      float p = bf2f((unsigned short)p8[j]);
      int dd = kt - lane;
      tot += p;
      ps0 += (dd <= -2) ? p : 0.f;
      ps1  = (dd == -1) ? p : ps1;
      ps2  = (dd ==  0) ? p : ps2;
      ps3  = (dd ==  1) ? p : ps3;
    }
  }
  float ps4 = tot - ps0 - ps1 - ps2 - ps3;

  // ---- V projection -> regA as St_V[hd][t] ----
  project(xv, wbf + 2 * WSZ + w * 32768, acc);
#pragma unroll
  for (int ni = 0; ni < 4; ++ni) {
    float bia = bv[64 * w + ni * 16 + l15];
    int hd = ni * 16 + l15;
#pragma unroll
    for (int mi = 0; mi < 4; ++mi) {
      unsigned int lo = (unsigned int)f2bf(acc[mi][ni][0] + bia) |
                        ((unsigned int)f2bf(acc[mi][ni][1] + bia) << 16);
      unsigned int hi = (unsigned int)f2bf(acc[mi][ni][2] + bia) |
                        ((unsigned int)f2bf(acc[mi][ni][3] + bia) << 16);
      uint2v pk; pk[0] = lo; pk[1] = hi;
      int off = (hd * 128 + (mi * 16 + lg * 4) * 2) ^ ((hd & 7) << 4);
      *(uint2v*)(regA + off) = pk;
    }
  }

  // ---- O^T = V * P^T (M=hd, N=qt, K=kt) ----
  f32x4 oacc[4][4];
#pragma unroll
  for (int mi = 0; mi < 4; ++mi)
#pragma unroll
    for (int ni = 0; ni < 4; ++ni) oacc[mi][ni] = fzero;
#pragma unroll
  for (int kk = 0; kk < 2; ++kk) {
    short8 av[4], bp[4];
#pragma unroll
    for (int mi = 0; mi < 4; ++mi) {
      int row = mi * 16 + l15;
      int off = (row * 128 + (kk * 32 + lg * 8) * 2) ^ ((row & 7) << 4);
      av[mi] = *(const short8*)(regA + off);
      bp[mi] = *(const short8*)(regB + off);
    }
#pragma unroll
    for (int ni = 0; ni < 4; ++ni)
#pragma unroll
      for (int mi = 0; mi < 4; ++mi)
        oacc[mi][ni] = __builtin_amdgcn_mfma_f32_16x16x32_bf16(av[mi], bp[ni],
                                                               oacc[mi][ni], 0, 0, 0);
  }

  // ---- O epilogue: +w2 (psum x rel_v), pack xo bf16 ----
  float psh0[4], psh1[4], psh2[4], psh3[4], psh4[4];
#pragma unroll
  for (int ni = 0; ni < 4; ++ni) {
    int qt2 = ni * 16 + l15;
    psh0[ni] = __shfl(ps0, qt2); psh1[ni] = __shfl(ps1, qt2); psh2[ni] = __shfl(ps2, qt2);
    psh3[ni] = __shfl(ps3, qt2); psh4[ni] = __shfl(ps4, qt2);
  }
  uint2v xop[4][4];
#pragma unroll
  for (int mi = 0; mi < 4; ++mi) {
    float rv_[4][5];
#pragma unroll
    for (int rr = 0; rr < 4; ++rr) {
      int hd = mi * 16 + lg * 4 + rr;
#pragma unroll
      for (int r = 0; r < 5; ++r) rv_[rr][r] = relv[r * 64 + hd];
    }
#pragma unroll
    for (int ni = 0; ni < 4; ++ni) {
      unsigned short u[4];
#pragma unroll
      for (int rr = 0; rr < 4; ++rr) {
        float w2 = psh0[ni] * rv_[rr][0] + psh1[ni] * rv_[rr][1] + psh2[ni] * rv_[rr][2]
                 + psh3[ni] * rv_[rr][3] + psh4[ni] * rv_[rr][4];
        u[rr] = f2bf(oacc[mi][ni][rr] + w2);
      }
      uint2v pk; pk[0] = u[0] | ((unsigned int)u[1] << 16);
      pk[1] = u[2] | ((unsigned int)u[3] << 16);
      xop[mi][ni] = pk;
    }
  }

  // ---- xo -> shared [t][d] (1KB rows, swz ^((t&15)<<4)); aliases waves 0-3 ----
  __syncthreads();
  char* xobuf = lds;               // 64 KB
#pragma unroll
  for (int ni = 0; ni < 4; ++ni) {
    int t = ni * 16 + l15;
#pragma unroll
    for (int mi = 0; mi < 4; ++mi) {
      int d = 64 * w + mi * 16 + lg * 4;
      int off = (t * 1024 + d * 2) ^ ((t & 15) << 4);
      *(uint2v*)(xobuf + off) = xop[mi][ni];
    }
  }
  __syncthreads();

  // ---- out = Wo xo + bo, *mask ----
  f32x4 cacc[4][4];
#pragma unroll
  for (int mi = 0; mi < 4; ++mi)
#pragma unroll
    for (int ni = 0; ni < 4; ++ni) cacc[mi][ni] = fzero;
  const unsigned short* wob = wbf + 3 * WSZ + w * 32768;
#pragma unroll
  for (int kk = 0; kk < 16; ++kk) {
    short8 ax[4], bw[4];
#pragma unroll
    for (int mi = 0; mi < 4; ++mi) {
      int t = mi * 16 + l15;
      int off = (t * 1024 + (kk * 32 + lg * 8) * 2) ^ ((t & 15) << 4);
      ax[mi] = *(const short8*)(xobuf + off);
    }
#pragma unroll
    for (int ni = 0; ni < 4; ++ni)
      bw[ni] = *(const short8*)(wob + kk * 2048 + ni * 512 + aoff);
#pragma unroll
    for (int ni = 0; ni < 4; ++ni)
#pragma unroll
      for (int mi = 0; mi < 4; ++mi)
        cacc[mi][ni] = __builtin_amdgcn_mfma_f32_16x16x32_bf16(ax[mi], bw[ni],
                                                               cacc[mi][ni], 0, 0, 0);
  }
#pragma unroll
  for (int mi = 0; mi < 4; ++mi) {
    int tl = mi * 16 + lg * 4;
    f32x4 mv = *(const f32x4*)(masks + (size_t)b * Tn + t0 + tl);
#pragma unroll
    for (int ni = 0; ni < 4; ++ni) {
      int o = 64 * w + ni * 16 + l15;
      float bia = bo[o];
      f32x4 r;
#pragma unroll
      for (int rr = 0; rr < 4; ++rr) r[rr] = (cacc[mi][ni][rr] + bia) * mv[rr];
      *(f32x4*)(out + ((size_t)b * Dm + o) * Tn + t0 + tl) = r;
    }
  }
}

// ===========================================================================
// Legacy round-1 path (fallback when ws_size cannot hold transposed tensors)
// ===========================================================================
__global__ void wcvt_kernel(const float* __restrict__ wq, const float* __restrict__ wk,
                            const float* __restrict__ wv, const float* __restrict__ wo,
                            unsigned short* __restrict__ dst) {
  int i = (blockIdx.x * blockDim.x + threadIdx.x) * 4;
  const float* src = (i < WSZ) ? wq : (i < 2 * WSZ) ? wk : (i < 3 * WSZ) ? wv : wo;
  int off = i & (WSZ - 1);
  f32x4 v = *(const f32x4*)(src + off);
  ushort4v o;
  o[0] = f2bf(v[0]); o[1] = f2bf(v[1]); o[2] = f2bf(v[2]); o[3] = f2bf(v[3]);
  *(ushort4v*)(dst + i) = o;
}

__global__ __launch_bounds__(512, 2)
void fused_kernel(const float* __restrict__ qx, const float* __restrict__ kx,
                  const float* __restrict__ vx, const float* __restrict__ masks,
                  const unsigned short* __restrict__ wbf,
                  const float* __restrict__ bq, const float* __restrict__ bk,
                  const float* __restrict__ bv, const float* __restrict__ bo,
                  const float* __restrict__ relk, const float* __restrict__ relv,
                  float* __restrict__ out)
{
  extern __shared__ char lds[];
  const int tid  = threadIdx.x;
  const int lane = tid & 63;
  const int w    = tid >> 6;
  const int l15  = lane & 15;
  const int lg   = lane >> 4;
  const int c    = blockIdx.x;
  const int b    = c >> 7;
  const int t0   = (c & (Gn - 1)) * NC;

  char* xbuf = lds;
  char* regA = lds + 16 * 1024 + w * 16 * 1024;
  char* regB = regA + 8 * 1024;

  float cmv = masks[(size_t)b * Tn + t0 + lane];
  unsigned long long nzb = __ballot(cmv != 0.0f);
  unsigned long long kpm = (nzb == 0ull) ? 0ull : __ballot(cmv == 0.0f);

  const f32x4 fzero = {0.f, 0.f, 0.f, 0.f};

  auto project = [&](const float* __restrict__ xin, const unsigned short* __restrict__ Wp,
                     f32x4 (&acc)[4][4]) {
#pragma unroll
    for (int mi = 0; mi < 4; ++mi)
#pragma unroll
      for (int ni = 0; ni < 4; ++ni) acc[mi][ni] = fzero;
    const size_t xbase = (size_t)b * Dm * Tn + t0 + lane;
    for (int s = 0; s < 4; ++s) {
      const int d0 = s * 128;
      short8 xs[2];
#pragma unroll
      for (int cc = 0; cc < 2; ++cc)
#pragma unroll
        for (int j = 0; j < 8; ++j) {
          float f = xin[xbase + (size_t)(d0 + 16 * w + 8 * cc + j) * Tn];
          xs[cc][j] = (short)f2bf(f);
        }
      short8 wf[4][4];
#pragma unroll
      for (int ni = 0; ni < 4; ++ni)
#pragma unroll
        for (int kk = 0; kk < 4; ++kk) {
          int o = 64 * w + ni * 16 + l15;
          int d = d0 + kk * 32 + lg * 8;
          wf[ni][kk] = *(const short8*)(Wp + o * Dm + d);
        }
      __syncthreads();
#pragma unroll
      for (int cc = 0; cc < 2; ++cc) {
        int off = (lane * 256 + (16 * w + 8 * cc) * 2) ^ ((lane & 15) << 4);
        *(short8*)(xbuf + off) = xs[cc];
      }
      __syncthreads();
#pragma unroll
      for (int kk = 0; kk < 4; ++kk) {
        short8 af[4];
#pragma unroll
        for (int mi = 0; mi < 4; ++mi) {
          int t = mi * 16 + l15;
          int off = (t * 256 + (kk * 32 + lg * 8) * 2) ^ ((t & 15) << 4);
          af[mi] = *(const short8*)(xbuf + off);
        }
#pragma unroll
        for (int ni = 0; ni < 4; ++ni)
#pragma unroll
          for (int mi = 0; mi < 4; ++mi)
            acc[mi][ni] = __builtin_amdgcn_mfma_f32_16x16x32_bf16(af[mi], wf[ni][kk],
                                                                  acc[mi][ni], 0, 0, 0);
      }
    }
  };

  f32x4 acc[4][4];

  project(qx, wbf + 0 * WSZ, acc);
#pragma unroll
  for (int ni = 0; ni < 4; ++ni) {
    float bia = bq[64 * w + ni * 16 + l15];
    int hd = ni * 16 + l15;
#pragma unroll
    for (int mi = 0; mi < 4; ++mi)
#pragma unroll
      for (int rr = 0; rr < 4; ++rr) {
        int t = mi * 16 + lg * 4 + rr;
        int off = (t * 128 + hd * 2) ^ ((t & 7) << 4);
        *(unsigned short*)(regA + off) = f2bf(acc[mi][ni][rr] + bia);
      }
  }

  project(kx, wbf + 1 * WSZ, acc);
#pragma unroll
  for (int ni = 0; ni < 4; ++ni) {
    float bia = bk[64 * w + ni * 16 + l15];
    int hd = ni * 16 + l15;
#pragma unroll
    for (int mi = 0; mi < 4; ++mi)
#pragma unroll
      for (int rr = 0; rr < 4; ++rr) {
        int t = mi * 16 + lg * 4 + rr;
        int off = (t * 128 + hd * 2) ^ ((t & 7) << 4);
        *(unsigned short*)(regB + off) = f2bf(acc[mi][ni][rr] + bia);
      }
  }

  f32x4 sacc[4][4];
#pragma unroll
  for (int mi = 0; mi < 4; ++mi)
#pragma unroll
    for (int ni = 0; ni < 4; ++ni) sacc[mi][ni] = fzero;
#pragma unroll
  for (int kk = 0; kk < 2; ++kk) {
    short8 aq[4], bkf[4];
#pragma unroll
    for (int mi = 0; mi < 4; ++mi) {
      int t = mi * 16 + l15;
      int off = (t * 128 + (kk * 32 + lg * 8) * 2) ^ ((t & 7) << 4);
      aq[mi]  = *(const short8*)(regA + off);
      bkf[mi] = *(const short8*)(regB + off);
    }
#pragma unroll
    for (int ni = 0; ni < 4; ++ni)
#pragma unroll
      for (int mi = 0; mi < 4; ++mi)
        sacc[mi][ni] = __builtin_amdgcn_mfma_f32_16x16x32_bf16(aq[mi], bkf[ni],
                                                               sacc[mi][ni], 0, 0, 0);
  }

  float qr0 = 0, qr1 = 0, qr2 = 0, qr3 = 0, qr4 = 0;
#pragma unroll
  for (int g = 0; g < 8; ++g) {
    short8 q8 = *(const short8*)(regA + ((lane * 128 + g * 16) ^ ((lane & 7) << 4)));
#pragma unroll
    for (int j = 0; j < 8; ++j) {
      float qf = bf2f((unsigned short)q8[j]);
      qr0 += qf * relk[0 * 64 + g * 8 + j];
      qr1 += qf * relk[1 * 64 + g * 8 + j];
      qr2 += qf * relk[2 * 64 + g * 8 + j];
      qr3 += qf * relk[3 * 64 + g * 8 + j];
      qr4 += qf * relk[4 * 64 + g * 8 + j];
    }
  }

  const float scale = 0.125f;
#pragma unroll
  for (int mi = 0; mi < 4; ++mi)
#pragma unroll
    for (int rr = 0; rr < 4; ++rr) {
      int qt = mi * 16 + lg * 4 + rr;
      float q0 = __shfl(qr0, qt), q1 = __shfl(qr1, qt), q2 = __shfl(qr2, qt),
            q3 = __shfl(qr3, qt), q4 = __shfl(qr4, qt);
      float sv[4];
#pragma unroll
      for (int ni = 0; ni < 4; ++ni) {
        int kt = ni * 16 + l15;
        int dd = kt - qt;
        float a2 = (dd <= -2) ? q0 : (dd == -1) ? q1 : (dd == 0) ? q2 : (dd == 1) ? q3 : q4;
        float s = (sacc[mi][ni][rr] + a2) * scale;
        if ((kpm >> kt) & 1ull) s = -1e30f;
        sv[ni] = s;
      }
      float m = fmaxf(fmaxf(sv[0], sv[1]), fmaxf(sv[2], sv[3]));
#pragma unroll
      for (int xm = 1; xm < 16; xm <<= 1) m = fmaxf(m, __shfl_xor(m, xm));
      float ssum = 0.f;
#pragma unroll
      for (int ni = 0; ni < 4; ++ni) { sv[ni] = __expf(sv[ni] - m); ssum += sv[ni]; }
#pragma unroll
      for (int xm = 1; xm < 16; xm <<= 1) ssum += __shfl_xor(ssum, xm);
      float inv = 1.0f / ssum;
#pragma unroll
      for (int ni = 0; ni < 4; ++ni) {
        int kt = ni * 16 + l15;
        int off = (qt * 128 + kt * 2) ^ ((qt & 7) << 4);
        *(unsigned short*)(regB + off) = f2bf(sv[ni] * inv);
      }
    }

  float ps0 = 0, ps1 = 0, ps2 = 0, ps3 = 0, tot = 0;
#pragma unroll
  for (int g = 0; g < 8; ++g) {
    short8 p8 = *(const short8*)(regB + ((lane * 128 + g * 16) ^ ((lane & 7) << 4)));
#pragma unroll
    for (int j = 0; j < 8; ++j) {
      int kt = g * 8 + j;
      float p = bf2f((unsigned short)p8[j]);
      int dd = kt - lane;
      tot += p;
      ps0 += (dd <= -2) ? p : 0.f;
      ps1  = (dd == -1) ? p : ps1;
      ps2  = (dd ==  0) ? p : ps2;
      ps3  = (dd ==  1) ? p : ps3;
    }
  }
  float ps4 = tot - ps0 - ps1 - ps2 - ps3;

  project(vx, wbf + 2 * WSZ, acc);
#pragma unroll
  for (int ni = 0; ni < 4; ++ni) {
    float bia = bv[64 * w + ni * 16 + l15];
    int hd = ni * 16 + l15;
#pragma unroll
    for (int mi = 0; mi < 4; ++mi) {
      unsigned int lo = (unsigned int)f2bf(acc[mi][ni][0] + bia) |
                        ((unsigned int)f2bf(acc[mi][ni][1] + bia) << 16);
      unsigned int hi = (unsigned int)f2bf(acc[mi][ni][2] + bia) |
                        ((unsigned int)f2bf(acc[mi][ni][3] + bia) << 16);
      uint2v pk; pk[0] = lo; pk[1] = hi;
      int off = (hd * 128 + (mi * 16 + lg * 4) * 2) ^ ((hd & 7) << 4);
      *(uint2v*)(regA + off) = pk;
    }
  }

  f32x4 oacc[4][4];
#pragma unroll
  for (int mi = 0; mi < 4; ++mi)
#pragma unroll
    for (int ni = 0; ni < 4; ++ni) oacc[mi][ni] = fzero;
#pragma unroll
  for (int kk = 0; kk < 2; ++kk) {
    short8 av[4], bp[4];
#pragma unroll
    for (int mi = 0; mi < 4; ++mi) {
      int row = mi * 16 + l15;
      int off = (row * 128 + (kk * 32 + lg * 8) * 2) ^ ((row & 7) << 4);
      av[mi] = *(const short8*)(regA + off);
      bp[mi] = *(const short8*)(regB + off);
    }
#pragma unroll
    for (int ni = 0; ni < 4; ++ni)
#pragma unroll
      for (int mi = 0; mi < 4; ++mi)
        oacc[mi][ni] = __builtin_amdgcn_mfma_f32_16x16x32_bf16(av[mi], bp[ni],
                                                               oacc[mi][ni], 0, 0, 0);
  }

  float psh0[4], psh1[4], psh2[4], psh3[4], psh4[4];
#pragma unroll
  for (int ni = 0; ni < 4; ++ni) {
    int qt2 = ni * 16 + l15;
    psh0[ni] = __shfl(ps0, qt2); psh1[ni] = __shfl(ps1, qt2); psh2[ni] = __shfl(ps2, qt2);
    psh3[ni] = __shfl(ps3, qt2); psh4[ni] = __shfl(ps4, qt2);
  }
  uint2v xop[4][4];
#pragma unroll
  for (int mi = 0; mi < 4; ++mi) {
    float rv_[4][5];
#pragma unroll
    for (int rr = 0; rr < 4; ++rr) {
      int hd = mi * 16 + lg * 4 + rr;
#pragma unroll
      for (int r = 0; r < 5; ++r) rv_[rr][r] = relv[r * 64 + hd];
    }
#pragma unroll
    for (int ni = 0; ni < 4; ++ni) {
      unsigned short u[4];
#pragma unroll
      for (int rr = 0; rr < 4; ++rr) {
        float w2 = psh0[ni] * rv_[rr][0] + psh1[ni] * rv_[rr][1] + psh2[ni] * rv_[rr][2]
                 + psh3[ni] * rv_[rr][3] + psh4[ni] * rv_[rr][4];
        u[rr] = f2bf(oacc[mi][ni][rr] + w2);
      }
      uint2v pk; pk[0] = u[0] | ((unsigned int)u[1] << 16);
      pk[1] = u[2] | ((unsigned int)u[3] << 16);
      xop[mi][ni] = pk;
    }
  }

  __syncthreads();
  char* xobuf = lds + 16 * 1024;
#pragma unroll
  for (int ni = 0; ni < 4; ++ni) {
    int t = ni * 16 + l15;
#pragma unroll
    for (int mi = 0; mi < 4; ++mi) {
      int d = 64 * w + mi * 16 + lg * 4;
      int off = (t * 1024 + d * 2) ^ ((t & 15) << 4);
      *(uint2v*)(xobuf + off) = xop[mi][ni];
    }
  }
  __syncthreads();

  f32x4 cacc[4][4];
#pragma unroll
  for (int mi = 0; mi < 4; ++mi)
#pragma unroll
    for (int ni = 0; ni < 4; ++ni) cacc[mi][ni] = fzero;
  const unsigned short* Wo = wbf + 3 * WSZ;
#pragma unroll
  for (int kk = 0; kk < 16; ++kk) {
    short8 ax[4], bw[4];
#pragma unroll
    for (int mi = 0; mi < 4; ++mi) {
      int t = mi * 16 + l15;
      int off = (t * 1024 + (kk * 32 + lg * 8) * 2) ^ ((t & 15) << 4);
      ax[mi] = *(const short8*)(xobuf + off);
    }
#pragma unroll
    for (int ni = 0; ni < 4; ++ni) {
      int o = 64 * w + ni * 16 + l15;
      bw[ni] = *(const short8*)(Wo + o * Dm + kk * 32 + lg * 8);
    }
#pragma unroll
    for (int ni = 0; ni < 4; ++ni)
#pragma unroll
      for (int mi = 0; mi < 4; ++mi)
        cacc[mi][ni] = __builtin_amdgcn_mfma_f32_16x16x32_bf16(ax[mi], bw[ni],
                                                               cacc[mi][ni], 0, 0, 0);
  }
#pragma unroll
  for (int mi = 0; mi < 4; ++mi) {
    int tl = mi * 16 + lg * 4;
    f32x4 mv = *(const f32x4*)(masks + (size_t)b * Tn + t0 + tl);
#pragma unroll
    for (int ni = 0; ni < 4; ++ni) {
      int o = 64 * w + ni * 16 + l15;
      float bia = bo[o];
      f32x4 r;
#pragma unroll
      for (int rr = 0; rr < 4; ++rr) r[rr] = (cacc[mi][ni][rr] + bia) * mv[rr];
      *(f32x4*)(out + ((size_t)b * Dm + o) * Tn + t0 + tl) = r;
    }
  }
}

// ---------------------------------------------------------------------------
extern "C" void kernel_launch(void* const* d_in, const int* in_sizes, int n_in,
                              void* d_out, int out_size, void* d_ws, size_t ws_size,
                              hipStream_t stream) {
  (void)in_sizes; (void)n_in; (void)out_size;
  const float* q  = (const float*)d_in[0];
  const float* k  = (const float*)d_in[1];
  const float* v  = (const float*)d_in[2];
  const float* ms = (const float*)d_in[3];
  const float* Wq = (const float*)d_in[4];
  const float* bq = (const float*)d_in[5];
  const float* Wk = (const float*)d_in[6];
  const float* bk = (const float*)d_in[7];
  const float* Wv = (const float*)d_in[8];
  const float* bv = (const float*)d_in[9];
  const float* Wo = (const float*)d_in[10];
  const float* bo = (const float*)d_in[11];
  const float* rk = (const float*)d_in[12];
  const float* rv = (const float*)d_in[13];
  float* out = (float*)d_out;

  unsigned short* wbf = (unsigned short*)d_ws;             // 2 MB tiled weights
  const size_t need = (size_t)4 * WSZ * 2 + 3 * XTSZ * 2;  // + 96 MB x-tiles

  if (ws_size >= need) {
    unsigned short* xt = wbf + 4 * WSZ;
    wcvt_tiled<<<dim3(1024), dim3(256), 0, stream>>>(Wq, Wk, Wv, Wo, wbf);
    xpose_kernel<<<dim3(12288), dim3(256), 0, stream>>>(q, k, v, xt);
    hipFuncSetAttribute((const void*)fused2_kernel,
                        hipFuncAttributeMaxDynamicSharedMemorySize, 131072);
    fused2_kernel<<<dim3(BG), dim3(512), 131072, stream>>>(xt, ms, wbf,
                                                           bq, bk, bv, bo, rk, rv, out);
  } else {
    wcvt_kernel<<<dim3(1024), dim3(256), 0, stream>>>(Wq, Wk, Wv, Wo, wbf);
    hipFuncSetAttribute((const void*)fused_kernel,
                        hipFuncAttributeMaxDynamicSharedMemorySize, 147456);
    fused_kernel<<<dim3(BG), dim3(512), 147456, stream>>>(q, k, v, ms, wbf,
                                                          bq, bk, bv, bo, rk, rv, out);
  }
}